// Round 1
// baseline (1120.446 us; speedup 1.0000x reference)
//
#include <hip/hip_runtime.h>
#include <cstdint>
#include <cstddef>

#define N_NODES 50000
#define N_EDGES 800000
#define DIM_H   128
#define DIM_P   64     // propagation width after commuting W3
#define DIM_OUT 1000
#define KHOPS   10
#define BN_EPS  1e-5f

static inline int ceil_div(int a, int b) { return (a + b - 1) / b; }

// ---------------- softmax over att[11] ----------------
__global__ void softmax11(const float* __restrict__ att, float* __restrict__ w) {
    if (threadIdx.x == 0) {
        float mx = att[0];
        for (int i = 1; i < KHOPS + 1; ++i) mx = fmaxf(mx, att[i]);
        float e[KHOPS + 1];
        float s = 0.f;
        for (int i = 0; i < KHOPS + 1; ++i) { e[i] = expf(att[i] - mx); s += e[i]; }
        for (int i = 0; i < KHOPS + 1; ++i) w[i] = e[i] / s;
    }
}

// ---------------- CSR build ----------------
__global__ void count_deg(const int* __restrict__ dst, int* __restrict__ deg, int ne) {
    int i = blockIdx.x * blockDim.x + threadIdx.x;
    if (i < ne) atomicAdd(&deg[dst[i]], 1);
}

__global__ __launch_bounds__(1024) void scan_rowptr(const int* __restrict__ deg,
                                                    int* __restrict__ row_ptr, int n) {
    __shared__ int tmp[1024];
    __shared__ int carry;
    if (threadIdx.x == 0) carry = 0;
    __syncthreads();
    for (int base = 0; base < n; base += 1024) {
        int i = base + threadIdx.x;
        int v = (i < n) ? deg[i] : 0;
        tmp[threadIdx.x] = v;
        __syncthreads();
        for (int off = 1; off < 1024; off <<= 1) {
            int t = (threadIdx.x >= off) ? tmp[threadIdx.x - off] : 0;
            __syncthreads();
            tmp[threadIdx.x] += t;
            __syncthreads();
        }
        int incl = tmp[threadIdx.x] + carry;
        if (i < n) row_ptr[i + 1] = incl;
        __syncthreads();
        if (threadIdx.x == 1023) carry = incl;
        __syncthreads();
    }
    if (threadIdx.x == 0) row_ptr[0] = 0;
}

__global__ void copy_int(const int* __restrict__ a, int* __restrict__ b, int n) {
    int i = blockIdx.x * blockDim.x + threadIdx.x;
    if (i < n) b[i] = a[i];
}

__global__ void fill_csr(const int* __restrict__ src, const int* __restrict__ dst,
                         int* __restrict__ cursor, int* __restrict__ col, int ne) {
    int i = blockIdx.x * blockDim.x + threadIdx.x;
    if (i < ne) {
        int d = dst[i];
        int pos = atomicAdd(&cursor[d], 1);
        col[pos] = src[i];
    }
}

// ---------------- GEMM: C[n,M] = A[n,KD] @ W[KD,M] (+bias) ----------------
// block: 256 threads, 64 rows x CPB cols per block.
// thread: 4 adjacent cols (cg) x RPT rows (rg). A tile in LDS (float4 broadcast
// reads), W read coalesced from global (L1/L2 resident), FMA-dominant inner loop.
template<int KD, int CPB>
__global__ __launch_bounds__(256) void gemm_bias(
    const float* __restrict__ A, const float* __restrict__ W,
    const float* __restrict__ bias, float* __restrict__ C, int n, int M) {
    constexpr int CG  = CPB / 4;     // col groups per block
    constexpr int RG  = 256 / CG;    // row groups
    constexpr int RPT = 64 / RG;     // rows per thread
    __shared__ float As[64][KD + 4];

    const int tid  = threadIdx.x;
    const int cg   = tid % CG;
    const int rg   = tid / CG;
    const int row0 = blockIdx.x * 64;
    const int col0 = blockIdx.y * CPB + cg * 4;

    // stage A tile (64 x KD)
    constexpr int VECS = 64 * KD / 4;
    for (int i = tid; i < VECS; i += 256) {
        int r  = i / (KD / 4);
        int k4 = (i % (KD / 4)) * 4;
        float4 v = make_float4(0.f, 0.f, 0.f, 0.f);
        int row = row0 + r;
        if (row < n) v = *reinterpret_cast<const float4*>(A + (size_t)row * KD + k4);
        *reinterpret_cast<float4*>(&As[r][k4]) = v;
    }
    __syncthreads();

    if (col0 + 3 >= M && col0 >= M) return;  // whole 4-col group OOB (M%4==0 so col0<M => col0+3<M)
    if (col0 >= M) return;

    float acc[RPT][4];
#pragma unroll
    for (int r = 0; r < RPT; ++r)
#pragma unroll
        for (int c = 0; c < 4; ++c) acc[r][c] = 0.f;

    for (int k4 = 0; k4 < KD; k4 += 4) {
        float4 w0 = *reinterpret_cast<const float4*>(W + (size_t)(k4 + 0) * M + col0);
        float4 w1 = *reinterpret_cast<const float4*>(W + (size_t)(k4 + 1) * M + col0);
        float4 w2 = *reinterpret_cast<const float4*>(W + (size_t)(k4 + 2) * M + col0);
        float4 w3 = *reinterpret_cast<const float4*>(W + (size_t)(k4 + 3) * M + col0);
#pragma unroll
        for (int r = 0; r < RPT; ++r) {
            float4 a = *reinterpret_cast<const float4*>(&As[rg * RPT + r][k4]);
            acc[r][0] += a.x * w0.x + a.y * w1.x + a.z * w2.x + a.w * w3.x;
            acc[r][1] += a.x * w0.y + a.y * w1.y + a.z * w2.y + a.w * w3.y;
            acc[r][2] += a.x * w0.z + a.y * w1.z + a.z * w2.z + a.w * w3.z;
            acc[r][3] += a.x * w0.w + a.y * w1.w + a.z * w2.w + a.w * w3.w;
        }
    }

    float4 b = make_float4(0.f, 0.f, 0.f, 0.f);
    if (bias) b = *reinterpret_cast<const float4*>(bias + col0);
#pragma unroll
    for (int r = 0; r < RPT; ++r) {
        int row = row0 + rg * RPT + r;
        if (row < n) {
            float4 o = make_float4(acc[r][0] + b.x, acc[r][1] + b.y,
                                   acc[r][2] + b.z, acc[r][3] + b.w);
            *reinterpret_cast<float4*>(C + (size_t)row * M + col0) = o;
        }
    }
}

// ---------------- BN column stats (sum, sumsq) in double ----------------
template<int M>
__global__ __launch_bounds__(256) void colstats(const float* __restrict__ Z,
                                                double* __restrict__ st, int n) {
    constexpr int RG = 256 / M;
    const int tid = threadIdx.x;
    const int c = tid % M, rg = tid / M;
    double s = 0.0, ss = 0.0;
    for (int row = blockIdx.x * RG + rg; row < n; row += gridDim.x * RG) {
        float v = Z[(size_t)row * M + c];
        s += v;
        ss += (double)v * (double)v;
    }
    __shared__ double sh[2][256];
    sh[0][tid] = s;
    sh[1][tid] = ss;
    __syncthreads();
    if (rg == 0) {
#pragma unroll
        for (int g = 1; g < RG; ++g) { s += sh[0][c + g * M]; ss += sh[1][c + g * M]; }
        atomicAdd(&st[c], s);
        atomicAdd(&st[M + c], ss);
    }
}

__global__ void bn_finalize(const double* __restrict__ st, const float* __restrict__ g,
                            const float* __restrict__ be, float* __restrict__ scsh,
                            int M, int n) {
    int c = threadIdx.x + blockIdx.x * blockDim.x;
    if (c < M) {
        double m = st[c] / n;
        double v = st[M + c] / n - m * m;
        float scale = g[c] * rsqrtf((float)v + BN_EPS);
        scsh[c]     = scale;
        scsh[M + c] = be[c] - (float)m * scale;
    }
}

// out = relu(Z*scale + shift) (+ residual)
template<int M, bool RES>
__global__ void bn_relu_kernel(const float* __restrict__ Z, const float* __restrict__ scsh,
                               const float* __restrict__ res, float* __restrict__ out, int total) {
    for (int i = blockIdx.x * blockDim.x + threadIdx.x; i < total;
         i += gridDim.x * blockDim.x) {
        int c = i & (M - 1);
        float v = fmaxf(Z[i] * scsh[c] + scsh[M + c], 0.f);
        if (RES) v += res[i];
        out[i] = v;
    }
}

// ---------------- propagation init: out_acc = w[0] * y ----------------
__global__ void scale_init(const float* __restrict__ y, const float* __restrict__ w,
                           float* __restrict__ o, int total) {
    float w0 = w[0];
    for (int i = blockIdx.x * blockDim.x + threadIdx.x; i < total;
         i += gridDim.x * blockDim.x)
        o[i] = w0 * y[i];
}

// ---------------- one propagation hop (CSR gather-sum, no atomics) -----------
// one wave (64 lanes = 64 features) per node; 4 nodes per 256-thread block
__global__ __launch_bounds__(256) void propagate(
    const float* __restrict__ cur, float* __restrict__ nxt, float* __restrict__ oacc,
    const int* __restrict__ row_ptr, const int* __restrict__ col,
    const float* __restrict__ wts, int hop, int n) {
    const int node = blockIdx.x * 4 + (threadIdx.x >> 6);
    const int f = threadIdx.x & 63;
    if (node >= n) return;
    const int beg = row_ptr[node], end = row_ptr[node + 1];
    float acc = 0.f;
    int e = beg;
    for (; e + 4 <= end; e += 4) {
        int s0 = col[e], s1 = col[e + 1], s2 = col[e + 2], s3 = col[e + 3];
        float a0 = cur[(size_t)s0 * DIM_P + f];
        float a1 = cur[(size_t)s1 * DIM_P + f];
        float a2 = cur[(size_t)s2 * DIM_P + f];
        float a3 = cur[(size_t)s3 * DIM_P + f];
        acc += (a0 + a1) + (a2 + a3);
    }
    for (; e < end; ++e) acc += cur[(size_t)col[e] * DIM_P + f];
    size_t o = (size_t)node * DIM_P + f;
    nxt[o] = acc;
    oacc[o] = fmaf(wts[hop], acc, oacc[o]);
}

// ---------------- launch ----------------
extern "C" void kernel_launch(void* const* d_in, const int* in_sizes, int n_in,
                              void* d_out, int out_size, void* d_ws, size_t ws_size,
                              hipStream_t stream) {
    const float* x    = (const float*)d_in[0];
    const int*   ei   = (const int*)  d_in[1];
    const float* W1   = (const float*)d_in[2];
    const float* g1   = (const float*)d_in[4];
    const float* be1  = (const float*)d_in[5];
    const float* W2   = (const float*)d_in[6];
    const float* g2   = (const float*)d_in[8];
    const float* be2  = (const float*)d_in[9];
    const float* att  = (const float*)d_in[10];
    const float* W3   = (const float*)d_in[11];
    const float* g3   = (const float*)d_in[13];
    const float* be3  = (const float*)d_in[14];
    const float* Wout = (const float*)d_in[15];
    const float* bout = (const float*)d_in[16];
    float* out = (float*)d_out;

    char* base = (char*)d_ws;
    size_t off = 0;
    auto alloc = [&](size_t bytes) -> void* {
        void* r = base + off;
        off += (bytes + 255) & ~(size_t)255;
        return r;
    };
    float*  f0      = (float*) alloc((size_t)N_NODES * DIM_H * 4); // z1/h1, later h3
    float*  f1      = (float*) alloc((size_t)N_NODES * DIM_H * 4); // z2/h2
    float*  yb      = (float*) alloc((size_t)N_NODES * DIM_P * 4); // y = h2@W3, ping
    float*  tb      = (float*) alloc((size_t)N_NODES * DIM_P * 4); // pong
    float*  oa      = (float*) alloc((size_t)N_NODES * DIM_P * 4); // weighted accumulator
    double* st      = (double*)alloc(640 * 8);                     // st1(256)+st2(256)+st3(128)
    float*  scsh    = (float*) alloc(768 * 4);
    float*  wts     = (float*) alloc(16 * 4);
    int*    row_ptr = (int*)   alloc((size_t)(N_NODES + 1) * 4);
    int*    deg     = (int*)   alloc((size_t)N_NODES * 4);         // later: cursor
    int*    col     = (int*)   alloc((size_t)N_EDGES * 4);

    const int* src = ei;
    const int* dst = ei + N_EDGES;
    double* st1 = st;       double* st2 = st + 256; double* st3 = st + 512;
    float*  sc1 = scsh;     float*  sc2 = scsh + 256; float* sc3 = scsh + 512;

    hipMemsetAsync(st, 0, 640 * 8, stream);
    hipMemsetAsync(deg, 0, (size_t)N_NODES * 4, stream);

    softmax11<<<1, 64, 0, stream>>>(att, wts);

    // CSR by destination
    count_deg<<<ceil_div(N_EDGES, 256), 256, 0, stream>>>(dst, deg, N_EDGES);
    scan_rowptr<<<1, 1024, 0, stream>>>(deg, row_ptr, N_NODES);
    copy_int<<<ceil_div(N_NODES, 256), 256, 0, stream>>>(row_ptr, deg, N_NODES);
    fill_csr<<<ceil_div(N_EDGES, 256), 256, 0, stream>>>(src, dst, deg, col, N_EDGES);

    const int RB = ceil_div(N_NODES, 64);

    // layer 1: z1 = x@W1 ; BN ; relu   (b1 cancels in BN)
    gemm_bias<128, 128><<<dim3(RB, 1), 256, 0, stream>>>(x, W1, nullptr, f0, N_NODES, DIM_H);
    colstats<128><<<256, 256, 0, stream>>>(f0, st1, N_NODES);
    bn_finalize<<<1, 128, 0, stream>>>(st1, g1, be1, sc1, 128, N_NODES);
    bn_relu_kernel<128, false><<<4096, 256, 0, stream>>>(f0, sc1, nullptr, f0, N_NODES * DIM_H);

    // layer 2: z2 = h1@W2 ; BN ; relu ; + h1
    gemm_bias<128, 128><<<dim3(RB, 1), 256, 0, stream>>>(f0, W2, nullptr, f1, N_NODES, DIM_H);
    colstats<128><<<256, 256, 0, stream>>>(f1, st2, N_NODES);
    bn_finalize<<<1, 128, 0, stream>>>(st2, g2, be2, sc2, 128, N_NODES);
    bn_relu_kernel<128, true><<<4096, 256, 0, stream>>>(f1, sc2, f0, f1, N_NODES * DIM_H);

    // commute W3 through the linear propagation: y = h2@W3 (64-dim hops)
    gemm_bias<128, 64><<<dim3(RB, 1), 256, 0, stream>>>(f1, W3, nullptr, yb, N_NODES, DIM_P);

    scale_init<<<4096, 256, 0, stream>>>(yb, wts, oa, N_NODES * DIM_P);

    float* cur = yb;
    float* nxt = tb;
    for (int hop = 1; hop <= KHOPS; ++hop) {
        propagate<<<ceil_div(N_NODES, 4), 256, 0, stream>>>(cur, nxt, oa, row_ptr, col,
                                                            wts, hop, N_NODES);
        float* t = cur; cur = nxt; nxt = t;
    }

    // layer 3 BN (b3 cancels) ; relu -> h3 (into f0, free since residual done)
    colstats<64><<<256, 256, 0, stream>>>(oa, st3, N_NODES);
    bn_finalize<<<1, 64, 0, stream>>>(st3, g3, be3, sc3, 64, N_NODES);
    bn_relu_kernel<64, false><<<4096, 256, 0, stream>>>(oa, sc3, nullptr, f0, N_NODES * DIM_P);

    // output: out = h3 @ Wout + bout
    gemm_bias<64, 128><<<dim3(RB, ceil_div(DIM_OUT, 128)), 256, 0, stream>>>(
        f0, Wout, bout, out, N_NODES, DIM_OUT);
}

// Round 2
// 1081.908 us; speedup vs baseline: 1.0356x; 1.0356x over previous
//
#include <hip/hip_runtime.h>
#include <cstdint>
#include <cstddef>

#define N_NODES 50000
#define N_EDGES 800000
#define DIM_H   128
#define DIM_P   64     // propagation width after commuting W3
#define DIM_OUT 1000
#define KHOPS   10
#define BN_EPS  1e-5f

static inline int ceil_div(int a, int b) { return (a + b - 1) / b; }

typedef short  bf16x8  __attribute__((ext_vector_type(8)));
typedef float  floatx4 __attribute__((ext_vector_type(4)));

__device__ __forceinline__ unsigned short f2bf_rne(float v) {
    unsigned int u = __float_as_uint(v);
    return (unsigned short)((u + 0x7fffu + ((u >> 16) & 1u)) >> 16);
}

// ---------------- softmax over att[11] ----------------
__global__ void softmax11(const float* __restrict__ att, float* __restrict__ w) {
    if (threadIdx.x == 0) {
        float mx = att[0];
        for (int i = 1; i < KHOPS + 1; ++i) mx = fmaxf(mx, att[i]);
        float e[KHOPS + 1];
        float s = 0.f;
        for (int i = 0; i < KHOPS + 1; ++i) { e[i] = expf(att[i] - mx); s += e[i]; }
        for (int i = 0; i < KHOPS + 1; ++i) w[i] = e[i] / s;
    }
}

// ---------------- CSR build ----------------
__global__ void count_deg(const int* __restrict__ dst, int* __restrict__ deg, int ne) {
    int i = blockIdx.x * blockDim.x + threadIdx.x;
    if (i < ne) atomicAdd(&deg[dst[i]], 1);
}

// local inclusive scan per 1024-block (shuffle-based, 3 barriers)
__global__ __launch_bounds__(1024) void scan_local(const int* __restrict__ deg,
                                                   int* __restrict__ row_ptr,
                                                   int* __restrict__ bsums, int n) {
    __shared__ int wsum[16];
    const int i = blockIdx.x * 1024 + threadIdx.x;
    const int lane = threadIdx.x & 63, w = threadIdx.x >> 6;
    int v = (i < n) ? deg[i] : 0;
    int s = v;
#pragma unroll
    for (int d = 1; d < 64; d <<= 1) {
        int t = __shfl_up(s, d, 64);
        if (lane >= d) s += t;
    }
    if (lane == 63) wsum[w] = s;
    __syncthreads();
    if (w == 0) {
        int x = (lane < 16) ? wsum[lane] : 0;
#pragma unroll
        for (int d = 1; d < 16; d <<= 1) {
            int t = __shfl_up(x, d, 64);
            if (lane >= d) x += t;
        }
        if (lane < 16) wsum[lane] = x;
    }
    __syncthreads();
    int incl = s + ((w > 0) ? wsum[w - 1] : 0);
    if (i < n) row_ptr[i + 1] = incl;
    if (threadIdx.x == 1023) bsums[blockIdx.x] = incl;
}

// exclusive scan of block sums (nb <= 64), single wave
__global__ void scan_bsums(int* __restrict__ bsums, int nb) {
    int lane = threadIdx.x;
    int v = (lane < nb) ? bsums[lane] : 0;
    int s = v;
#pragma unroll
    for (int d = 1; d < 64; d <<= 1) {
        int t = __shfl_up(s, d, 64);
        if (lane >= d) s += t;
    }
    if (lane < nb) bsums[lane] = s - v;
}

// add block offsets; also derive fill-cursor (exclusive start) in-place in deg
__global__ void scan_finish(int* __restrict__ row_ptr, int* __restrict__ deg,
                            const int* __restrict__ bsums, int n) {
    int i = blockIdx.x * blockDim.x + threadIdx.x;
    if (i < n) {
        int incl = row_ptr[i + 1] + bsums[i >> 10];
        row_ptr[i + 1] = incl;
        deg[i] = incl - deg[i];   // cursor = exclusive prefix
    }
    if (i == 0) row_ptr[0] = 0;
}

__global__ void fill_csr(const int* __restrict__ src, const int* __restrict__ dst,
                         int* __restrict__ cursor, int* __restrict__ col, int ne) {
    int i = blockIdx.x * blockDim.x + threadIdx.x;
    if (i < ne) {
        int d = dst[i];
        int pos = atomicAdd(&cursor[d], 1);
        col[pos] = src[i];
    }
}

// ---------------- GEMM: C[n,M] = A[n,KD] @ W[KD,M] (+bias) ----------------
template<int KD, int CPB>
__global__ __launch_bounds__(256) void gemm_bias(
    const float* __restrict__ A, const float* __restrict__ W,
    const float* __restrict__ bias, float* __restrict__ C, int n, int M) {
    constexpr int CG  = CPB / 4;     // col groups per block
    constexpr int RG  = 256 / CG;    // row groups
    constexpr int RPT = 64 / RG;     // rows per thread
    __shared__ float As[64][KD + 4];

    const int tid  = threadIdx.x;
    const int cg   = tid % CG;
    const int rg   = tid / CG;
    const int row0 = blockIdx.x * 64;
    const int col0 = blockIdx.y * CPB + cg * 4;

    constexpr int VECS = 64 * KD / 4;
    for (int i = tid; i < VECS; i += 256) {
        int r  = i / (KD / 4);
        int k4 = (i % (KD / 4)) * 4;
        float4 v = make_float4(0.f, 0.f, 0.f, 0.f);
        int row = row0 + r;
        if (row < n) v = *reinterpret_cast<const float4*>(A + (size_t)row * KD + k4);
        *reinterpret_cast<float4*>(&As[r][k4]) = v;
    }
    __syncthreads();

    if (col0 >= M) return;

    float acc[RPT][4];
#pragma unroll
    for (int r = 0; r < RPT; ++r)
#pragma unroll
        for (int c = 0; c < 4; ++c) acc[r][c] = 0.f;

    for (int k4 = 0; k4 < KD; k4 += 4) {
        float4 w0 = *reinterpret_cast<const float4*>(W + (size_t)(k4 + 0) * M + col0);
        float4 w1 = *reinterpret_cast<const float4*>(W + (size_t)(k4 + 1) * M + col0);
        float4 w2 = *reinterpret_cast<const float4*>(W + (size_t)(k4 + 2) * M + col0);
        float4 w3 = *reinterpret_cast<const float4*>(W + (size_t)(k4 + 3) * M + col0);
#pragma unroll
        for (int r = 0; r < RPT; ++r) {
            float4 a = *reinterpret_cast<const float4*>(&As[rg * RPT + r][k4]);
            acc[r][0] += a.x * w0.x + a.y * w1.x + a.z * w2.x + a.w * w3.x;
            acc[r][1] += a.x * w0.y + a.y * w1.y + a.z * w2.y + a.w * w3.y;
            acc[r][2] += a.x * w0.z + a.y * w1.z + a.z * w2.z + a.w * w3.z;
            acc[r][3] += a.x * w0.w + a.y * w1.w + a.z * w2.w + a.w * w3.w;
        }
    }

    float4 b = make_float4(0.f, 0.f, 0.f, 0.f);
    if (bias) b = *reinterpret_cast<const float4*>(bias + col0);
#pragma unroll
    for (int r = 0; r < RPT; ++r) {
        int row = row0 + rg * RPT + r;
        if (row < n) {
            float4 o = make_float4(acc[r][0] + b.x, acc[r][1] + b.y,
                                   acc[r][2] + b.z, acc[r][3] + b.w);
            *reinterpret_cast<float4*>(C + (size_t)row * M + col0) = o;
        }
    }
}

// ---------------- BN column stats (sum, sumsq) in double ----------------
template<int M>
__global__ __launch_bounds__(256) void colstats(const float* __restrict__ Z,
                                                double* __restrict__ st, int n) {
    constexpr int RG = 256 / M;
    const int tid = threadIdx.x;
    const int c = tid % M, rg = tid / M;
    double s = 0.0, ss = 0.0;
    for (int row = blockIdx.x * RG + rg; row < n; row += gridDim.x * RG) {
        float v = Z[(size_t)row * M + c];
        s += v;
        ss += (double)v * (double)v;
    }
    __shared__ double sh[2][256];
    sh[0][tid] = s;
    sh[1][tid] = ss;
    __syncthreads();
    if (rg == 0) {
#pragma unroll
        for (int g = 1; g < RG; ++g) { s += sh[0][c + g * M]; ss += sh[1][c + g * M]; }
        atomicAdd(&st[c], s);
        atomicAdd(&st[M + c], ss);
    }
}

__global__ void bn_finalize(const double* __restrict__ st, const float* __restrict__ g,
                            const float* __restrict__ be, float* __restrict__ scsh,
                            int M, int n) {
    int c = threadIdx.x + blockIdx.x * blockDim.x;
    if (c < M) {
        double m = st[c] / n;
        double v = st[M + c] / n - m * m;
        float scale = g[c] * rsqrtf((float)v + BN_EPS);
        scsh[c]     = scale;
        scsh[M + c] = be[c] - (float)m * scale;
    }
}

// out = relu(Z*scale + shift) (+ residual)
template<int M, bool RES>
__global__ void bn_relu_kernel(const float* __restrict__ Z, const float* __restrict__ scsh,
                               const float* __restrict__ res, float* __restrict__ out, int total) {
    for (int i = blockIdx.x * blockDim.x + threadIdx.x; i < total;
         i += gridDim.x * blockDim.x) {
        int c = i & (M - 1);
        float v = fmaxf(Z[i] * scsh[c] + scsh[M + c], 0.f);
        if (RES) v += res[i];
        out[i] = v;
    }
}

// ---------------- propagation init: out_acc = w[0] * y ----------------
__global__ void scale_init(const float* __restrict__ y, const float* __restrict__ w,
                           float* __restrict__ o, int total) {
    float w0 = w[0];
    for (int i = blockIdx.x * blockDim.x + threadIdx.x; i < total;
         i += gridDim.x * blockDim.x)
        o[i] = w0 * y[i];
}

// ---------------- one propagation hop (CSR gather-sum, no atomics) -----------
__global__ __launch_bounds__(256) void propagate(
    const float* __restrict__ cur, float* __restrict__ nxt, float* __restrict__ oacc,
    const int* __restrict__ row_ptr, const int* __restrict__ col,
    const float* __restrict__ wts, int hop, int n) {
    const int node = blockIdx.x * 4 + (threadIdx.x >> 6);
    const int f = threadIdx.x & 63;
    if (node >= n) return;
    const int beg = row_ptr[node], end = row_ptr[node + 1];
    float acc = 0.f;
    int e = beg;
    for (; e + 4 <= end; e += 4) {
        int s0 = col[e], s1 = col[e + 1], s2 = col[e + 2], s3 = col[e + 3];
        float a0 = cur[(size_t)s0 * DIM_P + f];
        float a1 = cur[(size_t)s1 * DIM_P + f];
        float a2 = cur[(size_t)s2 * DIM_P + f];
        float a3 = cur[(size_t)s3 * DIM_P + f];
        acc += (a0 + a1) + (a2 + a3);
    }
    for (; e < end; ++e) acc += cur[(size_t)col[e] * DIM_P + f];
    size_t o = (size_t)node * DIM_P + f;
    nxt[o] = acc;
    oacc[o] = fmaf(wts[hop], acc, oacc[o]);
}

// ---------------- Wout transpose + bf16 convert: WT[c][k] = bf16(W[k][c]) ----
__global__ void prep_wout(const float* __restrict__ W, unsigned short* __restrict__ WT) {
    int idx = blockIdx.x * blockDim.x + threadIdx.x;  // idx = c*64 + k
    if (idx < DIM_OUT * DIM_P) {
        int c = idx >> 6, k = idx & 63;
        WT[idx] = f2bf_rne(W[(size_t)k * DIM_OUT + c]);
    }
}

// ---------------- final GEMM via MFMA: out = relu(bn3(oa)) @ Wout + bout -----
// block = 4 waves; wave computes 16 rows x 16 cols, K=64 via two 16x16x32 MFMAs.
// A fragment: lane holds A[m=lane&15][k=(lane>>4)*8 + j]  (bn3+relu+bf16 fused)
// B fragment: lane holds B[k=(lane>>4)*8 + j][n=lane&15]  (from WT[n][k], 16B load)
// C/D: col=lane&15, row=(lane>>4)*4+reg  [m89-verified]
__global__ __launch_bounds__(256) void out_gemm_mfma(
    const float* __restrict__ oa, const float* __restrict__ scsh3,
    const unsigned short* __restrict__ WT, const float* __restrict__ bout,
    float* __restrict__ out) {
    const int wave = threadIdx.x >> 6;
    const int lane = threadIdx.x & 63;
    const int r0   = blockIdx.x * 16;
    const int c0   = blockIdx.y * 64 + wave * 16;
    if (c0 >= DIM_OUT) return;
    const int m    = lane & 15;
    const int quad = lane >> 4;
    const int kb   = quad * 8;
    const int row  = r0 + m;
    const int n    = c0 + m;

    const float* arow = oa + (size_t)row * DIM_P;
    bf16x8 afrag[2];
#pragma unroll
    for (int kh = 0; kh < 2; ++kh) {
        const int k0 = kh * 32 + kb;
        float4 a0 = *reinterpret_cast<const float4*>(arow + k0);
        float4 a1 = *reinterpret_cast<const float4*>(arow + k0 + 4);
        float4 s0 = *reinterpret_cast<const float4*>(scsh3 + k0);
        float4 s1 = *reinterpret_cast<const float4*>(scsh3 + k0 + 4);
        float4 h0 = *reinterpret_cast<const float4*>(scsh3 + DIM_P + k0);
        float4 h1 = *reinterpret_cast<const float4*>(scsh3 + DIM_P + k0 + 4);
        afrag[kh][0] = (short)f2bf_rne(fmaxf(a0.x * s0.x + h0.x, 0.f));
        afrag[kh][1] = (short)f2bf_rne(fmaxf(a0.y * s0.y + h0.y, 0.f));
        afrag[kh][2] = (short)f2bf_rne(fmaxf(a0.z * s0.z + h0.z, 0.f));
        afrag[kh][3] = (short)f2bf_rne(fmaxf(a0.w * s0.w + h0.w, 0.f));
        afrag[kh][4] = (short)f2bf_rne(fmaxf(a1.x * s1.x + h1.x, 0.f));
        afrag[kh][5] = (short)f2bf_rne(fmaxf(a1.y * s1.y + h1.y, 0.f));
        afrag[kh][6] = (short)f2bf_rne(fmaxf(a1.z * s1.z + h1.z, 0.f));
        afrag[kh][7] = (short)f2bf_rne(fmaxf(a1.w * s1.w + h1.w, 0.f));
    }

    bf16x8 bfrag[2];
    if (n < DIM_OUT) {
        const unsigned short* wrow = WT + (size_t)n * DIM_P;
        bfrag[0] = *reinterpret_cast<const bf16x8*>(wrow + kb);
        bfrag[1] = *reinterpret_cast<const bf16x8*>(wrow + 32 + kb);
    } else {
        bfrag[0] = bfrag[1] = (bf16x8)(short)0;
    }

    floatx4 acc = {0.f, 0.f, 0.f, 0.f};
    acc = __builtin_amdgcn_mfma_f32_16x16x32_bf16(afrag[0], bfrag[0], acc, 0, 0, 0);
    acc = __builtin_amdgcn_mfma_f32_16x16x32_bf16(afrag[1], bfrag[1], acc, 0, 0, 0);

    if (n < DIM_OUT) {
        const float bb = bout[n];
#pragma unroll
        for (int r = 0; r < 4; ++r) {
            const int rr = r0 + quad * 4 + r;
            out[(size_t)rr * DIM_OUT + n] = acc[r] + bb;
        }
    }
}

// ---------------- launch ----------------
extern "C" void kernel_launch(void* const* d_in, const int* in_sizes, int n_in,
                              void* d_out, int out_size, void* d_ws, size_t ws_size,
                              hipStream_t stream) {
    const float* x    = (const float*)d_in[0];
    const int*   ei   = (const int*)  d_in[1];
    const float* W1   = (const float*)d_in[2];
    const float* g1   = (const float*)d_in[4];
    const float* be1  = (const float*)d_in[5];
    const float* W2   = (const float*)d_in[6];
    const float* g2   = (const float*)d_in[8];
    const float* be2  = (const float*)d_in[9];
    const float* att  = (const float*)d_in[10];
    const float* W3   = (const float*)d_in[11];
    const float* g3   = (const float*)d_in[13];
    const float* be3  = (const float*)d_in[14];
    const float* Wout = (const float*)d_in[15];
    const float* bout = (const float*)d_in[16];
    float* out = (float*)d_out;

    char* base = (char*)d_ws;
    size_t off = 0;
    auto alloc = [&](size_t bytes) -> void* {
        void* r = base + off;
        off += (bytes + 255) & ~(size_t)255;
        return r;
    };
    float*  f0      = (float*) alloc((size_t)N_NODES * DIM_H * 4); // z1/h1
    float*  f1      = (float*) alloc((size_t)N_NODES * DIM_H * 4); // z2/h2
    float*  yb      = (float*) alloc((size_t)N_NODES * DIM_P * 4); // y = h2@W3, ping
    float*  tb      = (float*) alloc((size_t)N_NODES * DIM_P * 4); // pong
    float*  oa      = (float*) alloc((size_t)N_NODES * DIM_P * 4); // weighted accumulator
    double* st      = (double*)alloc(640 * 8);
    float*  scsh    = (float*) alloc(768 * 4);
    float*  wts     = (float*) alloc(16 * 4);
    int*    row_ptr = (int*)   alloc((size_t)(N_NODES + 1) * 4);
    int*    deg     = (int*)   alloc((size_t)N_NODES * 4);   // degree -> cursor
    int*    col     = (int*)   alloc((size_t)N_EDGES * 4);
    int*    bsums   = (int*)   alloc(64 * 4);
    unsigned short* WT = (unsigned short*)alloc((size_t)DIM_OUT * DIM_P * 2);

    const int* src = ei;
    const int* dst = ei + N_EDGES;
    double* st1 = st;   double* st2 = st + 256; double* st3 = st + 512;
    float*  sc1 = scsh; float*  sc2 = scsh + 256; float* sc3 = scsh + 512;

    hipMemsetAsync(st, 0, 640 * 8, stream);
    hipMemsetAsync(deg, 0, (size_t)N_NODES * 4, stream);

    softmax11<<<1, 64, 0, stream>>>(att, wts);
    prep_wout<<<ceil_div(DIM_OUT * DIM_P, 256), 256, 0, stream>>>(Wout, WT);

    // CSR by destination (fast 3-stage scan)
    count_deg<<<ceil_div(N_EDGES, 256), 256, 0, stream>>>(dst, deg, N_EDGES);
    const int NB = ceil_div(N_NODES, 1024);
    scan_local<<<NB, 1024, 0, stream>>>(deg, row_ptr, bsums, N_NODES);
    scan_bsums<<<1, 64, 0, stream>>>(bsums, NB);
    scan_finish<<<ceil_div(N_NODES, 256), 256, 0, stream>>>(row_ptr, deg, bsums, N_NODES);
    fill_csr<<<ceil_div(N_EDGES, 256), 256, 0, stream>>>(src, dst, deg, col, N_EDGES);

    const int RB = ceil_div(N_NODES, 64);

    // layer 1: z1 = x@W1 ; BN ; relu   (b1 cancels in BN)
    gemm_bias<128, 128><<<dim3(RB, 1), 256, 0, stream>>>(x, W1, nullptr, f0, N_NODES, DIM_H);
    colstats<128><<<256, 256, 0, stream>>>(f0, st1, N_NODES);
    bn_finalize<<<1, 128, 0, stream>>>(st1, g1, be1, sc1, 128, N_NODES);
    bn_relu_kernel<128, false><<<4096, 256, 0, stream>>>(f0, sc1, nullptr, f0, N_NODES * DIM_H);

    // layer 2: z2 = h1@W2 ; BN ; relu ; + h1
    gemm_bias<128, 128><<<dim3(RB, 1), 256, 0, stream>>>(f0, W2, nullptr, f1, N_NODES, DIM_H);
    colstats<128><<<256, 256, 0, stream>>>(f1, st2, N_NODES);
    bn_finalize<<<1, 128, 0, stream>>>(st2, g2, be2, sc2, 128, N_NODES);
    bn_relu_kernel<128, true><<<4096, 256, 0, stream>>>(f1, sc2, f0, f1, N_NODES * DIM_H);

    // commute W3 through the linear propagation: y = h2@W3 (64-dim hops)
    gemm_bias<128, 64><<<dim3(RB, 1), 256, 0, stream>>>(f1, W3, nullptr, yb, N_NODES, DIM_P);

    scale_init<<<4096, 256, 0, stream>>>(yb, wts, oa, N_NODES * DIM_P);

    float* cur = yb;
    float* nxt = tb;
    for (int hop = 1; hop <= KHOPS; ++hop) {
        propagate<<<ceil_div(N_NODES, 4), 256, 0, stream>>>(cur, nxt, oa, row_ptr, col,
                                                            wts, hop, N_NODES);
        float* t = cur; cur = nxt; nxt = t;
    }

    // layer 3 BN stats (b3 cancels); scale/shift fused into final GEMM A-load
    colstats<64><<<256, 256, 0, stream>>>(oa, st3, N_NODES);
    bn_finalize<<<1, 64, 0, stream>>>(st3, g3, be3, sc3, 64, N_NODES);

    // output: out = relu(bn3(oa)) @ Wout + bout   (bf16 MFMA)
    out_gemm_mfma<<<dim3(N_NODES / 16, ceil_div(DIM_OUT, 64)), 256, 0, stream>>>(
        oa, sc3, WT, bout, out);
}